// Round 14
// baseline (287.906 us; speedup 1.0000x reference)
//
#include <hip/hip_runtime.h>
#include <hip/hip_bf16.h>
#include <math.h>

#define SEQ 2048
#define DM 256
#define NH 8
#define DH 32

typedef unsigned short ushort_t;
typedef __attribute__((ext_vector_type(8))) unsigned short u16x8;
typedef __attribute__((ext_vector_type(8))) __bf16 b16x8;
typedef __attribute__((ext_vector_type(4))) float f32x4;

static __device__ __forceinline__ b16x8 as_b(u16x8 v) {
    union { u16x8 u; b16x8 b; } x; x.u = v; return x.b;
}
// f32 -> bf16 bits (RTN-even via native cast)
static __device__ __forceinline__ ushort_t f2bh(float f) {
    union { __bf16 b; ushort_t u; } x; x.b = (__bf16)f; return x.u;
}
// guaranteed single-instruction 2^x
static __device__ __forceinline__ float fast_exp2(float x) {
    float r; asm("v_exp_f32 %0, %1" : "=v"(r) : "v"(x)); return r;
}
// guaranteed packed f32x2 -> bf16x2 (lo=a, hi=b)
static __device__ __forceinline__ unsigned cvt_pk_bf16(float a, float b) {
    unsigned r; asm("v_cvt_pk_bf16_f32 %0, %1, %2" : "=v"(r) : "v"(a), "v"(b)); return r;
}
// load 8 f32, convert to bf16 fragment half
static __device__ __forceinline__ u16x8 ld8_f2b(const float* __restrict__ p) {
    float4 a = ((const float4*)p)[0];
    float4 b = ((const float4*)p)[1];
    union { unsigned u[4]; u16x8 v; } pk;
    pk.u[0] = cvt_pk_bf16(a.x, a.y);
    pk.u[1] = cvt_pk_bf16(a.z, a.w);
    pk.u[2] = cvt_pk_bf16(b.x, b.y);
    pk.u[3] = cvt_pk_bf16(b.z, b.w);
    return pk.v;
}

// ================= K1: proj2 MFMA + fused RoPE, fine-grained sync-free =================
// [R13 body, ld8_f2b now cvt_pk-based] grid (64 mb2, 16 nb), 256 thr = 4 independent waves.
__global__ __launch_bounds__(256) void k_proj2rope(
    const float* __restrict__ x, const float* __restrict__ Wq, const float* __restrict__ Wk,
    ushort_t* __restrict__ Qrot, ushort_t* __restrict__ Kbf, ushort_t* __restrict__ Vt,
    float* __restrict__ psum)
{
    const int t = (int)threadIdx.x;
    const int w = t >> 6, l = t & 63, g = l >> 4, ln = l & 15;
    const int mb2 = (int)blockIdx.x, nb = (int)blockIdx.y;
    const int rw0 = mb2 * 32 + (w & 1) * 16;
    const bool qpath = (nb < 8);
    const int col0 = (qpath ? nb : nb - 8) * 32;
    const int cw0 = col0 + (w >> 1) * 16;
    const int col = cw0 + ln;
    const float QSCALE = 0.25506807234f; // log2(e)/sqrt(32), folded into Qrot

    u16x8 af[8];
    const float* ap = x + (rw0 + ln) * DM + g * 8;
    #pragma unroll
    for (int kk = 0; kk < 8; ++kk) af[kk] = ld8_f2b(ap + kk * 32);

    const float* Wp = (qpath ? Wq : Wk) + col * DM + g * 8;
    f32x4 a0 = {0,0,0,0}, a1 = {0,0,0,0};
    #pragma unroll
    for (int kk = 0; kk < 8; kk += 2) {
        u16x8 b0 = ld8_f2b(Wp + kk * 32);
        u16x8 b1 = ld8_f2b(Wp + (kk + 1) * 32);
        a0 = __builtin_amdgcn_mfma_f32_16x16x32_bf16(as_b(af[kk]),     as_b(b0), a0, 0, 0, 0);
        a1 = __builtin_amdgcn_mfma_f32_16x16x32_bf16(as_b(af[kk + 1]), as_b(b1), a1, 0, 0, 0);
    }
    f32x4 acc = a0 + a1;

    if (qpath) {
        const int ch = col >> 1;
        const float inv = exp2f(-(float)ch * 0.10381025296522976f); // 10000^(-2c/256)
        const bool odd = (col & 1);
        const int rowgrp = mb2 * 32;
        #pragma unroll
        for (int r = 0; r < 4; ++r) {
            const int row = rw0 + 4 * g + r;
            float v = acc[r];
            int br = row & 31;
            int pos = ((br >> 2) & 3) * 8 + ((br >> 4) & 1) * 4 + (br & 3);
            Vt[col * SEQ + rowgrp + pos] = f2bh(v);
            float other = __shfl_xor(v, 1, 64);
            float ang = (float)row * inv;
            float sn, cs;
            __sincosf(ang, &sn, &cs);
            float xe = odd ? other : v;
            float xo = odd ? v : other;
            float o = odd ? (xe * sn + xo * cs) : (xe * cs - xo * sn);
            Qrot[row * DM + col] = f2bh(o * QSCALE);
        }
        float s = acc[0] + acc[1] + acc[2] + acc[3];
        s += __shfl_xor(s, 16, 64);
        s += __shfl_xor(s, 32, 64);
        if (g == 0) psum[(mb2 * 2 + (w & 1)) * DM + col] = s;
    } else {
        #pragma unroll
        for (int r = 0; r < 4; ++r)
            Kbf[(rw0 + 4 * g + r) * DM + col] = f2bh(acc[r]);
    }
}

// ================= K2: attention — asm exp2 + asm cvt_pk; REPS-instrumented ==============
// grid (64,8), 512 thr. Scores pre-scaled in log2 domain via Qrot (QSCALE folded).
__global__ __launch_bounds__(512, 4) void k_attn(
    const int* tp, const ushort_t* Qrot,
    const ushort_t* Kbf, const ushort_t* Vt,
    const float* psum, ushort_t* AObf, int reps)
{
    __shared__ float sl[2][8][64];
    __shared__ float sacc[2][8][64][9];   // +1 pad
    __shared__ float fixred[512];

    const int t = (int)threadIdx.x;
    const int w = t >> 6, l = t & 63, g = l >> 4, ln = l & 15;
    const int bb = (int)blockIdx.x, h = (int)blockIdx.y;
    const ushort_t* Kh = Kbf + h * DH;
    const ushort_t* Vh = Vt + (h * DH) * SEQ;

    for (int rep = 0; rep < reps; ++rep) {
    __syncthreads();

    if (bb == 0) {
        const int c32 = t & 31, seg = t >> 5;
        float partial = 0.f;
        #pragma unroll
        for (int r = 0; r < 8; ++r) partial += psum[(seg * 8 + r) * DM + h * 32 + c32];
        fixred[t] = partial;
        __syncthreads();
        if (t < 32) {
            float s = 0.f;
            #pragma unroll
            for (int sg = 0; sg < 16; ++sg) s += fixred[sg * 32 + t];
            AObf[2047 * DM + h * 32 + t] = f2bh(s * (1.0f / 2048.0f));
        }
    }

    const int uA = bb, uB = 127 - bb;
    const int qrowA = uA * 16 + ln, qrowB = uB * 16 + ln;
    const u16x8 qfA = *(const u16x8*)(Qrot + tp[qrowA] * DM + h * DH + g * 8);
    const u16x8 qfB = *(const u16x8*)(Qrot + tp[qrowB] * DM + h * DH + g * 8);
    const int loA = uA >> 2, loB = uB >> 2;
    const int n1 = 32 - loA;

    const int js = (w * 33) >> 3, je = ((w + 1) * 33) >> 3;
    const int aS = js, aE = (je < n1) ? je : n1;
    const int bS = (js > n1) ? js : n1, bE = je;

    #define SEGLOOP(U, QROW, KS, KE, LO)                                                     \
    {                                                                                        \
        float ls0 = 0.f, ls1 = 0.f, ls2 = 0.f, ls3 = 0.f;                                    \
        f32x4 acc0 = {0,0,0,0}, acc1 = {0,0,0,0};                                            \
        for (int kt = (KS); kt < (KE); ++kt) {                                               \
            u16x8 ka[4], va[4];                                                              \
            _Pragma("unroll")                                                                \
            for (int st = 0; st < 4; ++st)                                                   \
                ka[st] = *(const u16x8*)(Kh + (kt * 64 + st * 16 + ln) * DM + g * 8);        \
            _Pragma("unroll")                                                                \
            for (int c = 0; c < 2; ++c)                                                      \
                _Pragma("unroll")                                                            \
                for (int df = 0; df < 2; ++df)                                               \
                    va[c * 2 + df] = *(const u16x8*)(Vh + (df * 16 + ln) * SEQ + kt * 64 + c * 32 + g * 8); \
            f32x4 s4[4];                                                                     \
            _Pragma("unroll")                                                                \
            for (int st = 0; st < 4; ++st) {                                                 \
                f32x4 z = {0,0,0,0};                                                         \
                s4[st] = __builtin_amdgcn_mfma_f32_16x16x32_bf16(as_b(ka[st]), as_b(qf_), z, 0, 0, 0); \
            }                                                                                \
            float p[16];                                                                     \
            if (kt == (LO)) {                                                                \
                _Pragma("unroll")                                                            \
                for (int st = 0; st < 4; ++st)                                               \
                    _Pragma("unroll")                                                        \
                    for (int r = 0; r < 4; ++r) {                                            \
                        int kg = kt * 64 + st * 16 + g * 4 + r;                              \
                        float e = fast_exp2(s4[st][r]);                                      \
                        p[st * 4 + r] = (kg > (QROW)) ? e : 0.f;                             \
                    }                                                                        \
            } else {                                                                         \
                _Pragma("unroll")                                                            \
                for (int st = 0; st < 4; ++st)                                               \
                    _Pragma("unroll")                                                        \
                    for (int r = 0; r < 4; ++r)                                              \
                        p[st * 4 + r] = fast_exp2(s4[st][r]);                                \
            }                                                                                \
            ls0 += p[0] + p[4];  ls1 += p[1] + p[5];                                         \
            ls2 += p[2] + p[6];  ls3 += p[3] + p[7];                                         \
            ls0 += p[8] + p[12]; ls1 += p[9] + p[13];                                        \
            ls2 += p[10] + p[14]; ls3 += p[11] + p[15];                                      \
            _Pragma("unroll")                                                                \
            for (int c = 0; c < 2; ++c) {                                                    \
                union { unsigned u[4]; u16x8 v; } pk;                                        \
                _Pragma("unroll")                                                            \
                for (int j = 0; j < 4; ++j)                                                  \
                    pk.u[j] = cvt_pk_bf16(p[c * 8 + 2 * j], p[c * 8 + 2 * j + 1]);           \
                acc0 = __builtin_amdgcn_mfma_f32_16x16x32_bf16(as_b(va[c * 2 + 0]), as_b(pk.v), acc0, 0, 0, 0); \
                acc1 = __builtin_amdgcn_mfma_f32_16x16x32_bf16(as_b(va[c * 2 + 1]), as_b(pk.v), acc1, 0, 0, 0); \
            }                                                                                \
        }                                                                                    \
        sl[U][w][l] = (ls0 + ls1) + (ls2 + ls3);                                             \
        _Pragma("unroll")                                                                    \
        for (int r = 0; r < 4; ++r) { sacc[U][w][l][r] = acc0[r]; sacc[U][w][l][4 + r] = acc1[r]; } \
    }

    { const u16x8 qf_ = qfA; SEGLOOP(0, qrowA, loA + aS, loA + aE, loA) }
    { const u16x8 qf_ = qfB; SEGLOOP(1, qrowB, loB + (bS - n1), loB + (bE - n1), loB) }
    #undef SEGLOOP

    __syncthreads();

    if (w == 0 || w == 4) {
        const int u = w >> 2;
        const int qrow = u ? qrowB : qrowA;
        if (qrow != 2047) {
            float L = 0.f;
            #pragma unroll
            for (int sw = 0; sw < 8; ++sw)
                #pragma unroll
                for (int gg = 0; gg < 4; ++gg)
                    L += sl[u][sw][gg * 16 + ln];
            float invL = 1.0f / L;
            ushort_t* o = AObf + qrow * DM + h * DH;
            #pragma unroll
            for (int r = 0; r < 4; ++r) {
                float o0 = 0.f, o1 = 0.f;
                #pragma unroll
                for (int sw = 0; sw < 8; ++sw) {
                    o0 += sacc[u][sw][l][r];
                    o1 += sacc[u][sw][l][4 + r];
                }
                o[4 * g + r]      = f2bh(o0 * invL);
                o[16 + 4 * g + r] = f2bh(o1 * invL);
            }
        }
    }
    } // rep
}

// ================= K3: proj1 MFMA, split-K across wave pairs =================
// [R13 body unchanged]
__global__ __launch_bounds__(256) void k_proj1(
    const ushort_t* __restrict__ AObf, const float* __restrict__ Wo,
    float* __restrict__ out)
{
    __shared__ float part[2][64][5];   // [rowhalf][lane][r], +1 pad
    const int t = (int)threadIdx.x;
    const int w = t >> 6, l = t & 63, g = l >> 4, ln = l & 15;
    const int mb2 = (int)blockIdx.x, nb = (int)blockIdx.y;
    const int rw0 = mb2 * 32 + (w & 1) * 16;
    const int col0 = nb * 16;
    const int kh = w >> 1;

    u16x8 af[4];
    const ushort_t* ap = AObf + (rw0 + ln) * DM + kh * 128 + g * 8;
    #pragma unroll
    for (int kk = 0; kk < 4; ++kk) af[kk] = *(const u16x8*)(ap + kk * 32);

    const float* Wp = Wo + (col0 + ln) * DM + kh * 128 + g * 8;
    f32x4 a0 = {0,0,0,0}, a1 = {0,0,0,0};
    #pragma unroll
    for (int kk = 0; kk < 4; kk += 2) {
        u16x8 b0 = ld8_f2b(Wp + kk * 32);
        u16x8 b1 = ld8_f2b(Wp + (kk + 1) * 32);
        a0 = __builtin_amdgcn_mfma_f32_16x16x32_bf16(as_b(af[kk]),     as_b(b0), a0, 0, 0, 0);
        a1 = __builtin_amdgcn_mfma_f32_16x16x32_bf16(as_b(af[kk + 1]), as_b(b1), a1, 0, 0, 0);
    }
    f32x4 acc = a0 + a1;

    if (kh == 0) {
        #pragma unroll
        for (int r = 0; r < 4; ++r) part[w & 1][l][r] = acc[r];
    }
    __syncthreads();
    if (kh == 1) {
        const int col = col0 + ln;
        #pragma unroll
        for (int r = 0; r < 4; ++r)
            out[(rw0 + 4 * g + r) * DM + col] = acc[r] + part[w & 1][l][r];
    }
}

extern "C" void kernel_launch(void* const* d_in, const int* in_sizes, int n_in,
                              void* d_out, int out_size, void* d_ws, size_t ws_size,
                              hipStream_t stream) {
    const float* x  = (const float*)d_in[0];
    const int*   tp = (const int*)d_in[1];
    const float* Wq = (const float*)d_in[2];
    const float* Wk = (const float*)d_in[3];
    // d_in[4] = v_weight — UNUSED (reference computes x_v with q_weight)
    const float* Wo = (const float*)d_in[5];
    float* out = (float*)d_out;

    float* ws = (float*)d_ws;
    float*    psum = ws;                          // 128*256 f32
    ushort_t* Qrot = (ushort_t*)(ws + 32768);     // 2048*256 bf16 (rotated, pre-scaled)
    ushort_t* Kbf  = (ushort_t*)(ws + 294912);    // 2048*256 bf16
    ushort_t* Vt   = (ushort_t*)(ws + 557056);    // [256][2048] bf16, pi-permuted
    ushort_t* AObf = (ushort_t*)(ws + 819200);    // 2048*256 bf16

    const int REPS = 16;  // attn x16 (idempotent) to read its exact per-rep time; projs single
    k_proj2rope<<<dim3(64, 16), 256, 0, stream>>>(x, Wq, Wk, Qrot, Kbf, Vt, psum);
    k_attn<<<dim3(64, 8), 512, 0, stream>>>(tp, Qrot, Kbf, Vt, psum, AObf, REPS);
    k_proj1<<<dim3(64, 16), 256, 0, stream>>>(AObf, Wo, out);
}

// Round 15
// 46.938 us; speedup vs baseline: 6.1338x; 6.1338x over previous
//
#include <hip/hip_runtime.h>
#include <hip/hip_bf16.h>
#include <math.h>

#define SEQ 2048
#define DM 256
#define NH 8
#define DH 32

typedef unsigned short ushort_t;
typedef __attribute__((ext_vector_type(8))) unsigned short u16x8;
typedef __attribute__((ext_vector_type(8))) __bf16 b16x8;
typedef __attribute__((ext_vector_type(4))) float f32x4;

static __device__ __forceinline__ b16x8 as_b(u16x8 v) {
    union { u16x8 u; b16x8 b; } x; x.u = v; return x.b;
}
// f32 -> bf16 bits (RTN-even via native cast)
static __device__ __forceinline__ ushort_t f2bh(float f) {
    union { __bf16 b; ushort_t u; } x; x.b = (__bf16)f; return x.u;
}
// guaranteed single-instruction 2^x
static __device__ __forceinline__ float fast_exp2(float x) {
    float r; asm("v_exp_f32 %0, %1" : "=v"(r) : "v"(x)); return r;
}
// guaranteed packed f32x2 -> bf16x2 (lo=a, hi=b)
static __device__ __forceinline__ unsigned cvt_pk_bf16(float a, float b) {
    unsigned r; asm("v_cvt_pk_bf16_f32 %0, %1, %2" : "=v"(r) : "v"(a), "v"(b)); return r;
}
// load 8 f32, convert to bf16 fragment half
static __device__ __forceinline__ u16x8 ld8_f2b(const float* __restrict__ p) {
    float4 a = ((const float4*)p)[0];
    float4 b = ((const float4*)p)[1];
    union { unsigned u[4]; u16x8 v; } pk;
    pk.u[0] = cvt_pk_bf16(a.x, a.y);
    pk.u[1] = cvt_pk_bf16(a.z, a.w);
    pk.u[2] = cvt_pk_bf16(b.x, b.y);
    pk.u[3] = cvt_pk_bf16(b.z, b.w);
    return pk.v;
}

// ================= K1: proj2 MFMA + fused RoPE, XCD-affine grid =================
// grid (16 nb, 64 mb2): XCD = id%8 = nb%8 -> head h's K (nb=8+h) and V/Q cols (nb=h)
// are produced on XCD h, where attn for head h will consume them.
__global__ __launch_bounds__(256) void k_proj2rope(
    const float* __restrict__ x, const float* __restrict__ Wq, const float* __restrict__ Wk,
    ushort_t* __restrict__ Qrot, ushort_t* __restrict__ Kbf, ushort_t* __restrict__ Vt,
    float* __restrict__ psum)
{
    const int t = (int)threadIdx.x;
    const int w = t >> 6, l = t & 63, g = l >> 4, ln = l & 15;
    const int nb = (int)blockIdx.x, mb2 = (int)blockIdx.y;
    const int rw0 = mb2 * 32 + (w & 1) * 16;
    const bool qpath = (nb < 8);
    const int col0 = (qpath ? nb : nb - 8) * 32;
    const int cw0 = col0 + (w >> 1) * 16;
    const int col = cw0 + ln;
    const float QSCALE = 0.25506807234f; // log2(e)/sqrt(32), folded into Qrot

    u16x8 af[8];
    const float* ap = x + (rw0 + ln) * DM + g * 8;
    #pragma unroll
    for (int kk = 0; kk < 8; ++kk) af[kk] = ld8_f2b(ap + kk * 32);

    const float* Wp = (qpath ? Wq : Wk) + col * DM + g * 8;
    f32x4 a0 = {0,0,0,0}, a1 = {0,0,0,0};
    #pragma unroll
    for (int kk = 0; kk < 8; kk += 2) {
        u16x8 b0 = ld8_f2b(Wp + kk * 32);
        u16x8 b1 = ld8_f2b(Wp + (kk + 1) * 32);
        a0 = __builtin_amdgcn_mfma_f32_16x16x32_bf16(as_b(af[kk]),     as_b(b0), a0, 0, 0, 0);
        a1 = __builtin_amdgcn_mfma_f32_16x16x32_bf16(as_b(af[kk + 1]), as_b(b1), a1, 0, 0, 0);
    }
    f32x4 acc = a0 + a1;

    if (qpath) {
        const int ch = col >> 1;
        const float inv = exp2f(-(float)ch * 0.10381025296522976f); // 10000^(-2c/256)
        const bool odd = (col & 1);
        const int rowgrp = mb2 * 32;
        #pragma unroll
        for (int r = 0; r < 4; ++r) {
            const int row = rw0 + 4 * g + r;
            float v = acc[r];
            int br = row & 31;
            int pos = ((br >> 2) & 3) * 8 + ((br >> 4) & 1) * 4 + (br & 3);
            Vt[col * SEQ + rowgrp + pos] = f2bh(v);
            float other = __shfl_xor(v, 1, 64);
            float ang = (float)row * inv;
            float sn, cs;
            __sincosf(ang, &sn, &cs);
            float xe = odd ? other : v;
            float xo = odd ? v : other;
            float o = odd ? (xe * sn + xo * cs) : (xe * cs - xo * sn);
            Qrot[row * DM + col] = f2bh(o * QSCALE);
        }
        float s = acc[0] + acc[1] + acc[2] + acc[3];
        s += __shfl_xor(s, 16, 64);
        s += __shfl_xor(s, 32, 64);
        if (g == 0) psum[(mb2 * 2 + (w & 1)) * DM + col] = s;
    } else {
        #pragma unroll
        for (int r = 0; r < 4; ++r)
            Kbf[(rw0 + 4 * g + r) * DM + col] = f2bh(acc[r]);
    }
}

// ================= K2: attention, XCD head-affinity grid (8 h, 64 bb) =================
// id%8 = h -> all 64 blocks of head h on XCD h; K/V/Q slices stay XCD-local L2.
__global__ __launch_bounds__(512, 4) void k_attn(
    const int* __restrict__ tp, const ushort_t* __restrict__ Qrot,
    const ushort_t* __restrict__ Kbf, const ushort_t* __restrict__ Vt,
    const float* __restrict__ psum, ushort_t* __restrict__ AObf)
{
    __shared__ float sl[2][8][64];
    __shared__ float sacc[2][8][64][9];   // +1 pad
    __shared__ float fixred[512];

    const int t = (int)threadIdx.x;
    const int w = t >> 6, l = t & 63, g = l >> 4, ln = l & 15;
    const int h = (int)blockIdx.x, bb = (int)blockIdx.y;
    const ushort_t* Kh = Kbf + h * DH;
    const ushort_t* Vh = Vt + (h * DH) * SEQ;

    if (bb == 0) {
        // row 2047 = column mean of V (fully-masked softmax), this head's 32 cols
        const int c32 = t & 31, seg = t >> 5;
        float partial = 0.f;
        #pragma unroll
        for (int r = 0; r < 8; ++r) partial += psum[(seg * 8 + r) * DM + h * 32 + c32];
        fixred[t] = partial;
        __syncthreads();
        if (t < 32) {
            float s = 0.f;
            #pragma unroll
            for (int sg = 0; sg < 16; ++sg) s += fixred[sg * 32 + t];
            AObf[2047 * DM + h * 32 + t] = f2bh(s * (1.0f / 2048.0f));
        }
    }

    const int uA = bb, uB = 127 - bb;
    const int qrowA = uA * 16 + ln, qrowB = uB * 16 + ln;
    const u16x8 qfA = *(const u16x8*)(Qrot + tp[qrowA] * DM + h * DH + g * 8);
    const u16x8 qfB = *(const u16x8*)(Qrot + tp[qrowB] * DM + h * DH + g * 8);
    const int loA = uA >> 2, loB = uB >> 2;
    const int n1 = 32 - loA;

    const int js = (w * 33) >> 3, je = ((w + 1) * 33) >> 3;
    const int aS = js, aE = (je < n1) ? je : n1;
    const int bS = (js > n1) ? js : n1, bE = je;

    #define SEGLOOP(U, QROW, KS, KE, LO)                                                     \
    {                                                                                        \
        float ls0 = 0.f, ls1 = 0.f, ls2 = 0.f, ls3 = 0.f;                                    \
        f32x4 acc0 = {0,0,0,0}, acc1 = {0,0,0,0};                                            \
        for (int kt = (KS); kt < (KE); ++kt) {                                               \
            u16x8 ka[4], va[4];                                                              \
            _Pragma("unroll")                                                                \
            for (int st = 0; st < 4; ++st)                                                   \
                ka[st] = *(const u16x8*)(Kh + (kt * 64 + st * 16 + ln) * DM + g * 8);        \
            _Pragma("unroll")                                                                \
            for (int c = 0; c < 2; ++c)                                                      \
                _Pragma("unroll")                                                            \
                for (int df = 0; df < 2; ++df)                                               \
                    va[c * 2 + df] = *(const u16x8*)(Vh + (df * 16 + ln) * SEQ + kt * 64 + c * 32 + g * 8); \
            f32x4 s4[4];                                                                     \
            _Pragma("unroll")                                                                \
            for (int st = 0; st < 4; ++st) {                                                 \
                f32x4 z = {0,0,0,0};                                                         \
                s4[st] = __builtin_amdgcn_mfma_f32_16x16x32_bf16(as_b(ka[st]), as_b(qf_), z, 0, 0, 0); \
            }                                                                                \
            float p[16];                                                                     \
            if (kt == (LO)) {                                                                \
                _Pragma("unroll")                                                            \
                for (int st = 0; st < 4; ++st)                                               \
                    _Pragma("unroll")                                                        \
                    for (int r = 0; r < 4; ++r) {                                            \
                        int kg = kt * 64 + st * 16 + g * 4 + r;                              \
                        float e = fast_exp2(s4[st][r]);                                      \
                        p[st * 4 + r] = (kg > (QROW)) ? e : 0.f;                             \
                    }                                                                        \
            } else {                                                                         \
                _Pragma("unroll")                                                            \
                for (int st = 0; st < 4; ++st)                                               \
                    _Pragma("unroll")                                                        \
                    for (int r = 0; r < 4; ++r)                                              \
                        p[st * 4 + r] = fast_exp2(s4[st][r]);                                \
            }                                                                                \
            ls0 += p[0] + p[4];  ls1 += p[1] + p[5];                                         \
            ls2 += p[2] + p[6];  ls3 += p[3] + p[7];                                         \
            ls0 += p[8] + p[12]; ls1 += p[9] + p[13];                                        \
            ls2 += p[10] + p[14]; ls3 += p[11] + p[15];                                      \
            _Pragma("unroll")                                                                \
            for (int c = 0; c < 2; ++c) {                                                    \
                union { unsigned u[4]; u16x8 v; } pk;                                        \
                _Pragma("unroll")                                                            \
                for (int j = 0; j < 4; ++j)                                                  \
                    pk.u[j] = cvt_pk_bf16(p[c * 8 + 2 * j], p[c * 8 + 2 * j + 1]);           \
                acc0 = __builtin_amdgcn_mfma_f32_16x16x32_bf16(as_b(va[c * 2 + 0]), as_b(pk.v), acc0, 0, 0, 0); \
                acc1 = __builtin_amdgcn_mfma_f32_16x16x32_bf16(as_b(va[c * 2 + 1]), as_b(pk.v), acc1, 0, 0, 0); \
            }                                                                                \
        }                                                                                    \
        sl[U][w][l] = (ls0 + ls1) + (ls2 + ls3);                                             \
        _Pragma("unroll")                                                                    \
        for (int r = 0; r < 4; ++r) { sacc[U][w][l][r] = acc0[r]; sacc[U][w][l][4 + r] = acc1[r]; } \
    }

    { const u16x8 qf_ = qfA; SEGLOOP(0, qrowA, loA + aS, loA + aE, loA) }
    { const u16x8 qf_ = qfB; SEGLOOP(1, qrowB, loB + (bS - n1), loB + (bE - n1), loB) }
    #undef SEGLOOP

    __syncthreads();

    if (w == 0 || w == 4) {
        const int u = w >> 2;
        const int qrow = u ? qrowB : qrowA;
        if (qrow != 2047) {
            float L = 0.f;
            #pragma unroll
            for (int sw = 0; sw < 8; ++sw)
                #pragma unroll
                for (int gg = 0; gg < 4; ++gg)
                    L += sl[u][sw][gg * 16 + ln];
            float invL = 1.0f / L;
            ushort_t* o = AObf + qrow * DM + h * DH;
            #pragma unroll
            for (int r = 0; r < 4; ++r) {
                float o0 = 0.f, o1 = 0.f;
                #pragma unroll
                for (int sw = 0; sw < 8; ++sw) {
                    o0 += sacc[u][sw][l][r];
                    o1 += sacc[u][sw][l][4 + r];
                }
                o[4 * g + r]      = f2bh(o0 * invL);
                o[16 + 4 * g + r] = f2bh(o1 * invL);
            }
        }
    }
}

// ================= K3: proj1 MFMA, split-K across wave pairs =================
// [R14 body unchanged]
__global__ __launch_bounds__(256) void k_proj1(
    const ushort_t* __restrict__ AObf, const float* __restrict__ Wo,
    float* __restrict__ out)
{
    __shared__ float part[2][64][5];   // [rowhalf][lane][r], +1 pad
    const int t = (int)threadIdx.x;
    const int w = t >> 6, l = t & 63, g = l >> 4, ln = l & 15;
    const int mb2 = (int)blockIdx.x, nb = (int)blockIdx.y;
    const int rw0 = mb2 * 32 + (w & 1) * 16;
    const int col0 = nb * 16;
    const int kh = w >> 1;

    u16x8 af[4];
    const ushort_t* ap = AObf + (rw0 + ln) * DM + kh * 128 + g * 8;
    #pragma unroll
    for (int kk = 0; kk < 4; ++kk) af[kk] = *(const u16x8*)(ap + kk * 32);

    const float* Wp = Wo + (col0 + ln) * DM + kh * 128 + g * 8;
    f32x4 a0 = {0,0,0,0}, a1 = {0,0,0,0};
    #pragma unroll
    for (int kk = 0; kk < 4; kk += 2) {
        u16x8 b0 = ld8_f2b(Wp + kk * 32);
        u16x8 b1 = ld8_f2b(Wp + (kk + 1) * 32);
        a0 = __builtin_amdgcn_mfma_f32_16x16x32_bf16(as_b(af[kk]),     as_b(b0), a0, 0, 0, 0);
        a1 = __builtin_amdgcn_mfma_f32_16x16x32_bf16(as_b(af[kk + 1]), as_b(b1), a1, 0, 0, 0);
    }
    f32x4 acc = a0 + a1;

    if (kh == 0) {
        #pragma unroll
        for (int r = 0; r < 4; ++r) part[w & 1][l][r] = acc[r];
    }
    __syncthreads();
    if (kh == 1) {
        const int col = col0 + ln;
        #pragma unroll
        for (int r = 0; r < 4; ++r)
            out[(rw0 + 4 * g + r) * DM + col] = acc[r] + part[w & 1][l][r];
    }
}

extern "C" void kernel_launch(void* const* d_in, const int* in_sizes, int n_in,
                              void* d_out, int out_size, void* d_ws, size_t ws_size,
                              hipStream_t stream) {
    const float* x  = (const float*)d_in[0];
    const int*   tp = (const int*)d_in[1];
    const float* Wq = (const float*)d_in[2];
    const float* Wk = (const float*)d_in[3];
    // d_in[4] = v_weight — UNUSED (reference computes x_v with q_weight)
    const float* Wo = (const float*)d_in[5];
    float* out = (float*)d_out;

    float* ws = (float*)d_ws;
    float*    psum = ws;                          // 128*256 f32
    ushort_t* Qrot = (ushort_t*)(ws + 32768);     // 2048*256 bf16 (rotated, pre-scaled)
    ushort_t* Kbf  = (ushort_t*)(ws + 294912);    // 2048*256 bf16
    ushort_t* Vt   = (ushort_t*)(ws + 557056);    // [256][2048] bf16, pi-permuted
    ushort_t* AObf = (ushort_t*)(ws + 819200);    // 2048*256 bf16

    k_proj2rope<<<dim3(16, 64), 256, 0, stream>>>(x, Wq, Wk, Qrot, Kbf, Vt, psum);
    k_attn<<<dim3(8, 64), 512, 0, stream>>>(tp, Qrot, Kbf, Vt, psum, AObf);
    k_proj1<<<dim3(64, 16), 256, 0, stream>>>(AObf, Wo, out);
}